// Round 11
// baseline (3837.897 us; speedup 1.0000x reference)
//
#include <hip/hip_runtime.h>
#include <float.h>
#include <math.h>

#define B_    128
#define H_    512
#define V_    1000
#define T_    256
#define G4_   2048
#define NBLK  256          // cooperative launch: 1 block/CU
#define SPIN_MAX (1 << 17) // bounded spin: converts would-be hang into wrong-answer

typedef unsigned long long ull;

#define AT_LOAD(p)    __hip_atomic_load((p), __ATOMIC_RELAXED, __HIP_MEMORY_SCOPE_AGENT)
#define AT_STORE(p,v) __hip_atomic_store((p), (v), __ATOMIC_RELAXED, __HIP_MEMORY_SCOPE_AGENT)

// Packed-fp32 vector type: float2 arithmetic contracts to v_pk_fma_f32 on
// gfx950 (r10: issue time 7.6 -> 5.2 us/step).
typedef float f2 __attribute__((ext_vector_type(2)));

// Pin a 64-bit f2 in a VGPR pair (r7: stops weight-load rematerialization).
#define PINF2(v_) asm volatile("" : "+v"(v_))

// 2-step DPP quad reduction (r9): lane holds sum over its 4-lane quad.
__device__ __forceinline__ float red4(float x) {
  x += __int_as_float(__builtin_amdgcn_mov_dpp(__float_as_int(x), 0xB1, 0xF, 0xF, true)); // xor1
  x += __int_as_float(__builtin_amdgcn_mov_dpp(__float_as_int(x), 0x4E, 0xF, 0xF, true)); // xor2
  return x;
}

// Fast overflow-safe transcendentals (map to v_exp_f32/v_rcp_f32).
__device__ __forceinline__ float fsigmoid(float x) {
  return 1.f / (1.f + __expf(-x));
}
__device__ __forceinline__ float ftanh(float x) {
  const float e = __expf(2.f * fabsf(x));
  return copysignf(1.f - 2.f / (e + 1.f), x);
}

// ---------------------------------------------------------------------------
// Precompute GEMM:  C = A[M][0:512] * Bm[N][koff:+512]^T (+bias1+bias2).
// ileave=1 stores gate-interleaved: C[m][ (n&511)*4 + (n>>9) ]  (ldc=2048).
// ---------------------------------------------------------------------------
__global__ __launch_bounds__(256) void gemm_nt_k512(
    const float* __restrict__ A, int M,
    const float* __restrict__ Bm, int ldb, int koff,
    const float* __restrict__ bias1, const float* __restrict__ bias2,
    float* __restrict__ C, int ldc, int ileave)
{
  __shared__ float As[16][68];
  __shared__ float Bs[16][68];
  const int tid = threadIdx.x;
  const int m0 = blockIdx.y * 64, n0 = blockIdx.x * 64;
  const int tm = tid & 15, tn = tid >> 4;
  const int lm = tid & 63, kq = tid >> 6;
  float acc[4][4] = {};
  for (int k0 = 0; k0 < 512; k0 += 16) {
    float4 av = make_float4(0.f, 0.f, 0.f, 0.f);
    if (m0 + lm < M) av = *(const float4*)(A + (size_t)(m0 + lm) * 512 + k0 + kq * 4);
    float4 bv = *(const float4*)(Bm + (size_t)(n0 + lm) * ldb + koff + k0 + kq * 4);
    __syncthreads();
    As[kq*4+0][lm] = av.x; As[kq*4+1][lm] = av.y; As[kq*4+2][lm] = av.z; As[kq*4+3][lm] = av.w;
    Bs[kq*4+0][lm] = bv.x; Bs[kq*4+1][lm] = bv.y; Bs[kq*4+2][lm] = bv.z; Bs[kq*4+3][lm] = bv.w;
    __syncthreads();
#pragma unroll
    for (int kk = 0; kk < 16; ++kk) {
      const float4 a = *(const float4*)&As[kk][tm * 4];
      const float4 b = *(const float4*)&Bs[kk][tn * 4];
      const float aa[4] = {a.x, a.y, a.z, a.w};
      const float bb[4] = {b.x, b.y, b.z, b.w};
#pragma unroll
      for (int i = 0; i < 4; ++i)
#pragma unroll
        for (int j = 0; j < 4; ++j)
          acc[i][j] = fmaf(aa[i], bb[j], acc[i][j]);
    }
  }
#pragma unroll
  for (int i = 0; i < 4; ++i) {
    const int m = m0 + tm * 4 + i;
    if (m < M) {
#pragma unroll
      for (int j = 0; j < 4; ++j) {
        const int n = n0 + tn * 4 + j;
        float v = acc[i][j];
        if (bias1) v += bias1[n];
        if (bias2) v += bias2[n];
        const size_t idx = ileave ? ((size_t)m * ldc + (size_t)(n & 511) * 4 + (n >> 9))
                                  : ((size_t)m * ldc + n);
        C[idx] = v;
      }
    }
  }
}

// ---------------------------------------------------------------------------
// init: tagged h-exchange buffer hx[2][B][H] of 8B words [h:f32|tag:32].
//  slot1 = context with tag 1 (= tag(-1)); slot0 tags cleared to 0.
//  amax: parity-1 seeded with tag 1 + start token; parity-0 tags cleared
//  (fixes latent cross-run stale-tag race present since r4).
// amax word: [val:f32 | tag:16 | token:16]; tag(t) = t+2.
// ---------------------------------------------------------------------------
__global__ __launch_bounds__(256) void init_kernel(
    const float* __restrict__ ctx, ull* __restrict__ hx,
    ull* __restrict__ amax, const int* __restrict__ start_id)
{
  const int i = blockIdx.x * blockDim.x + threadIdx.x;   // 0..16383
#pragma unroll
  for (int k = 0; k < 4; ++k) {
    const int j = i + k * 16384;                          // 0..65535 = row*512+unit
    hx[(size_t)B_ * H_ + j] =
        (((ull)__float_as_uint(ctx[j])) << 32) | 1u;      // slot1: context, tag 1
    hx[j] = 0ull;                                         // slot0: tag 0
  }
  if (i < B_ * 32) {
    const int m = i & 31;
    amax[(size_t)B_ * 32 + i] = (m == 0)
        ? ((((ull)__float_as_uint(FLT_MAX)) << 32) | (1u << 16) | (unsigned)(*start_id))
        : ((((ull)__float_as_uint(-FLT_MAX)) << 32) | (1u << 16));
    amax[i] = ((ull)__float_as_uint(-FLT_MAX)) << 32;     // slot0: tag 0
  }
}

// ---------------------------------------------------------------------------
// Persistent cooperative decoder, 512 threads (8 waves, 2/SIMD).
// 8 groups x 32 blocks; group g owns rows [16g,16g+16).  Tagged-dataflow sync.
//
// Round-11 changes vs r10 (2696us):
//  * TAGGED h EXCHANGE: h travels as 8B [value|tag] words.  D stores its
//    slice tagged; F polls the words DIRECTLY.  Removes the hdone flag
//    round-trip, phase E, and 2 barriers -> the exchange is one store->load
//    trip.  (Same single-word-atomicity argument as the proven amax path.)
//  * 3 barriers/step (post-B, post-F, post-P2), was 5-6.
//  * proj[token] gather prefetched in B into LDS gproj (tok is in all 32
//    lanes after the butterfly) -> D's gather latency hides under barrier 1.
//  * Everything else = r10: pk_fma f2 dots, red4 quad partials + gq/lq,
//    stride-20 hs, pinned weights, fast transcendentals, bounded spins.
// ---------------------------------------------------------------------------
__global__ __launch_bounds__(512, 2) void decoder_main(
    const float* __restrict__ Whh,
    const float* __restrict__ Wout,
    const float* __restrict__ bout,
    const float* __restrict__ proj,
    const float* __restrict__ basep,
    ull* __restrict__ hx,
    ull* __restrict__ amax,
    float* __restrict__ out)
{
  __shared__ struct alignas(16) SM {
    float hs[16][640];          // h tile: chunk cc at col cc*20 (16 used, 4 pad)
    float gbase[16][68];        // interleaved basep slice [r][u*4+g]
    float gproj[16][68];        // interleaved proj[token] slice (staged in B)
    float gq[2][16][324];       // gate quad-partials [par][r][u*20 + g*4 + quad]
    float lq[2][16][132];       // logit quad-partials [par][r][j*4 + quad]
    float sbout[32];
  } sm;

  const int tid  = threadIdx.x;
  const int bid  = blockIdx.x;
  const int gid  = bid >> 5;     // group: rows [16g, 16g+16)
  const int mem  = bid & 31;     // member: units [16*mem,+16) / vocab [32*mem,+32)
  const int lane = tid & 63;
  const int w    = tid >> 6;     // wave 0..7
  const int row_base = gid * 16;
  const int vb   = mem * 32;

  const int q1  = lane >> 4;     // 0..3
  const int kc  = lane & 15;     // 16-float K-chunk within the K-half
  const int i3  = kc & 3;        // which output this lane stores
  const int quad = kc >> 2;      // quad-partial index
  const int blk = w & 3;         // gate index / vocab-octet
  const int par = w >> 2;        // K-half 0/1
  const int hoff  = par * 256 + kc * 16;     // K offset in weights (logical)
  const int hcol  = (par * 16 + kc) * 20;    // hs column of this chunk
  const int scol  = (tid >> 4) * 20 + (tid & 15);  // staging col: unit 'tid'

  // per-lane store offsets (within a row plane)
  const int goff = (q1 * 4 + i3) * 20 + blk * 4 + quad;   // gq: conflict-free
  const int loff = (blk * 8 + q1 * 2 + i3) * 4 + quad;    // lq (i3<2 only)

  // ---- one-time preloads: weights -> f2 register pairs, PINNED -----------
  f2 w1p[4][8];                  // 4 gate-lines x 16 floats = 64 VGPR
#pragma unroll
  for (int i = 0; i < 4; ++i) {
    const f2* p = (const f2*)(Whh + (size_t)(blk * 512 + mem * 16 + q1 * 4 + i) * H_ + hoff);
#pragma unroll
    for (int j = 0; j < 8; ++j) w1p[i][j] = p[j];
  }
  const int v0 = vb + blk * 8 + q1 * 2;
  f2 w2p[2][8];                  // 2 vocab x 16 floats = 32 VGPR
#pragma unroll
  for (int jj = 0; jj < 2; ++jj) {
    const int vv = (v0 + jj < V_) ? (v0 + jj) : (V_ - 1);
    const f2* p = (const f2*)(Wout + (size_t)vv * H_ + hoff);
#pragma unroll
    for (int j = 0; j < 8; ++j) w2p[jj][j] = p[j];
  }
#pragma unroll
  for (int i = 0; i < 4; ++i)
#pragma unroll
    for (int j = 0; j < 8; ++j) PINF2(w1p[i][j]);
#pragma unroll
  for (int jj = 0; jj < 2; ++jj)
#pragma unroll
    for (int j = 0; j < 8; ++j) PINF2(w2p[jj][j]);

  // basep slice (interleaved) -> LDS; bout slice -> LDS
#pragma unroll
  for (int kx = 0; kx < 2; ++kx) {
    const int e = tid + kx * 512;
    const int r = e >> 6, c = e & 63;
    sm.gbase[r][c] = basep[(size_t)(row_base + r) * G4_ + mem * 64 + c];
  }
  if (tid < 32) sm.sbout[tid] = (vb + tid < V_) ? bout[vb + tid] : 0.f;

  float c_reg = 0.f;   // tid<256 owns cell (row=row_base+(tid>>4), unit=mem*16+(tid&15))
  const size_t BTVo = (size_t)B_ * T_ * V_;

  // ---- prepass: stage h(-1)=context from hx slot1 (ready by launch order) -
  {
    const ull* hq = hx + (size_t)B_ * H_ + (size_t)row_base * H_;
    ull v[16];
#pragma unroll
    for (int i = 0; i < 16; ++i) v[i] = AT_LOAD(&hq[i * 512 + tid]);
#pragma unroll
    for (int i = 0; i < 16; ++i)
      sm.hs[i][scol] = __uint_as_float((unsigned)(v[i] >> 32));
  }
  __syncthreads();

  for (int t = 0; t < T_; ++t) {
    ull* hxw = hx + (size_t)(t & 1) * (B_ * H_);

    // ---- P1: gates(t) quad-partials = Whh_half * h(t-1) -> gq[par] -------
#pragma unroll 2
    for (int r = 0; r < 16; ++r) {
      const f2* hr = (const f2*)&sm.hs[r][hcol];
      f2 c0 = {0.f, 0.f}, c1 = {0.f, 0.f}, c2 = {0.f, 0.f}, c3 = {0.f, 0.f};
#pragma unroll
      for (int j = 0; j < 8; ++j) {
        const f2 hv = hr[j];
        c0 = w1p[0][j] * hv + c0;   // v_pk_fma_f32
        c1 = w1p[1][j] * hv + c1;
        c2 = w1p[2][j] * hv + c2;
        c3 = w1p[3][j] * hv + c3;
      }
      float a0 = c0.x + c0.y;
      float a1 = c1.x + c1.y;
      float a2 = c2.x + c2.y;
      float a3 = c3.x + c3.y;
      a0 = red4(a0); a1 = red4(a1); a2 = red4(a2); a3 = red4(a3);
      const float av = (i3 == 0) ? a0 : (i3 == 1) ? a1 : (i3 == 2) ? a2 : a3;
      sm.gq[par][r][goff] = av;
    }

    // ---- B: poll amax(t-1) -> token; prefetch proj[token] -> gproj -------
    {
      const int prow = tid >> 5, pj = tid & 31;
      const unsigned expect = (unsigned)(t + 1) << 16;   // tag(t-1) = t+1
      const ull* ap =
          amax + ((size_t)((t + 1) & 1) * B_ + row_base + prow) * 32;
      ull wv = AT_LOAD(&ap[pj]);
      for (int it = 0; (((unsigned)wv ^ expect) & 0xFFFF0000u) && it < SPIN_MAX; ++it) {
        __builtin_amdgcn_s_sleep(1);
        wv = AT_LOAD(&ap[pj]);
      }
      __atomic_signal_fence(__ATOMIC_ACQ_REL);
      float v  = __uint_as_float((unsigned)(wv >> 32));
      int   ix = (int)((unsigned)wv & 0xFFFFu);
#pragma unroll
      for (int d = 16; d >= 1; d >>= 1) {
        const float vo = __shfl_xor(v, d, 32);
        const int   io = __shfl_xor(ix, d, 32);
        if (vo > v || (vo == v && io < ix)) { v = vo; ix = io; }
      }
      const int tk = (ix >= 0 && ix < V_) ? ix : 0;      // clamp: no OOB ever
      if (pj < 16) {                                     // 16 float4s = full row
        const float4 gp = *(const float4*)&proj[(size_t)tk * G4_ +
                                                (size_t)(mem * 16 + pj) * 4];
        *(float4*)&sm.gproj[prow][pj * 4] = gp;
      }
    }
    __syncthreads();   // barrier 1: gq/gproj ready; hs reads (P1) complete

    // ---- D: LSTM epilogue (tid<256); h stored TAGGED (no flag needed) ----
    if (tid < 256) {
      const int rl = tid >> 4, ul = tid & 15;
      float gate[4];
#pragma unroll
      for (int g = 0; g < 4; ++g) {
        const float4 qa = *(const float4*)&sm.gq[0][rl][ul * 20 + g * 4];
        const float4 qb = *(const float4*)&sm.gq[1][rl][ul * 20 + g * 4];
        gate[g] = ((qa.x + qa.y) + (qa.z + qa.w)) + ((qb.x + qb.y) + (qb.z + qb.w));
      }
      const float4 gc = *(const float4*)&sm.gbase[rl][ul * 4];
      const float4 gp = *(const float4*)&sm.gproj[rl][ul * 4];
      const float gx = gate[0] + gc.x + gp.x;
      const float gy = gate[1] + gc.y + gp.y;
      const float gz = gate[2] + gc.z + gp.z;
      const float gw = gate[3] + gc.w + gp.w;
      const float ig = fsigmoid(gx);
      const float fg = fsigmoid(gy);
      const float gg = ftanh(gz);
      const float og = fsigmoid(gw);
      const float cn = fg * c_reg + ig * gg;
      c_reg = cn;
      const float hn = og * ftanh(cn);
      const int row = row_base + rl, hid = mem * 16 + ul;
      AT_STORE(&hxw[(size_t)row * H_ + hid],
               (((ull)__float_as_uint(hn)) << 32) | (unsigned)(t + 2));
      if (t == T_ - 1) {
        out[BTVo + (size_t)row * H_ + hid] = hn;                    // h_f
        out[BTVo + (size_t)B_ * H_ + (size_t)row * H_ + hid] = cn;  // c_f
      }
    }

    // ---- F: poll tagged h(t) words from all members; stage into hs -------
    // (no barrier needed before: hs reads finished at barrier 1; polls
    //  self-synchronize against all 32 writers)
    {
      const ull* hq = hxw + (size_t)row_base * H_;
      const unsigned tagv = (unsigned)(t + 2);
      ull v[16];
#pragma unroll
      for (int i = 0; i < 16; ++i) v[i] = AT_LOAD(&hq[i * 512 + tid]);
#pragma unroll
      for (int i = 0; i < 16; ++i) {
        int it = 0;
        while ((unsigned)v[i] != tagv && it < SPIN_MAX) {
          __builtin_amdgcn_s_sleep(1);
          v[i] = AT_LOAD(&hq[i * 512 + tid]);
          ++it;
        }
      }
      __atomic_signal_fence(__ATOMIC_ACQ_REL);
#pragma unroll
      for (int i = 0; i < 16; ++i)
        sm.hs[i][scol] = __uint_as_float((unsigned)(v[i] >> 32));
    }
    __syncthreads();   // barrier 2: hs(t) staged

    // ---- P2: logits(t) quad-partials = Wout_half * h(t) -> lq[par] ------
#pragma unroll 2
    for (int r = 0; r < 16; ++r) {
      const f2* hr = (const f2*)&sm.hs[r][hcol];
      f2 c0 = {0.f, 0.f}, c1 = {0.f, 0.f};
#pragma unroll
      for (int j = 0; j < 8; ++j) {
        const f2 hv = hr[j];
        c0 = w2p[0][j] * hv + c0;   // v_pk_fma_f32
        c1 = w2p[1][j] * hv + c1;
      }
      float b0 = c0.x + c0.y;
      float b1 = c1.x + c1.y;
      b0 = red4(b0); b1 = red4(b1);
      if (i3 < 2)
        sm.lq[par][r][loff] = (i3 == 0) ? b0 : b1;
    }
    __syncthreads();   // barrier 3: lq ready

    // ---- H: sum 8 quad-partials, write logits, argmax -> amax -----------
    {
      const int r = tid >> 5, j = tid & 31;
      const float4 qa = *(const float4*)&sm.lq[0][r][j * 4];
      const float4 qb = *(const float4*)&sm.lq[1][r][j * 4];
      float v = ((qa.x + qa.y) + (qa.z + qa.w)) +
                ((qb.x + qb.y) + (qb.z + qb.w)) + sm.sbout[j];
      if (vb + j < V_)
        out[((size_t)(row_base + r) * T_ + t) * V_ + vb + j] = v;
      else
        v = -FLT_MAX;
      int ix = j;
#pragma unroll
      for (int d = 16; d >= 1; d >>= 1) {
        const float vo = __shfl_xor(v, d, 32);
        const int   io = __shfl_xor(ix, d, 32);
        if (vo > v || (vo == v && io < ix)) { v = vo; ix = io; }
      }
      if (j == 0) {
        const ull pk =
            (((ull)__float_as_uint(v)) << 32) |
            ((unsigned)(t + 2) << 16) | (unsigned)(vb + ix);
        AT_STORE(&amax[((size_t)(t & 1) * B_ + row_base + r) * 32 + mem], pk);
      }
    }
    // no barrier: next P1 reads hs (stable until next F, which is past
    // barrier 1) and writes gq (last read by D(t), completed before barrier 2)
  }
}

// ---------------------------------------------------------------------------
extern "C" void kernel_launch(void* const* d_in, const int* in_sizes, int n_in,
                              void* d_out, int out_size, void* d_ws, size_t ws_size,
                              hipStream_t stream)
{
  const float* ctx   = (const float*)d_in[0];
  const float* emb   = (const float*)d_in[1];
  const float* Wih   = (const float*)d_in[2];
  const float* bih   = (const float*)d_in[3];
  const float* Whh   = (const float*)d_in[4];
  const float* bhh   = (const float*)d_in[5];
  const float* Wout  = (const float*)d_in[6];
  const float* bout  = (const float*)d_in[7];
  const int*   start = (const int*)d_in[8];
  float* out = (float*)d_out;

  // workspace layout (bytes)
  char* ws = (char*)d_ws;
  float* proj  = (float*)(ws + 0);                    // 1000*2048*4 = 8,192,000
  float* basep = (float*)(ws + 8192000);              // 128*2048*4  = 1,048,576
  ull*   hx    = (ull*)(ws + 9240576);                // 2*128*512*8 = 1,048,576
  ull*   amax  = (ull*)(ws + 10289152);               // 2*128*32*8  =    65,536
  // total: 10,354,688 bytes

  hipLaunchKernelGGL(gemm_nt_k512, dim3(32, 2), dim3(256), 0, stream,
                     ctx, B_, Wih, 1024, 0, bih, bhh, basep, G4_, 1);
  hipLaunchKernelGGL(gemm_nt_k512, dim3(32, 16), dim3(256), 0, stream,
                     emb, V_, Wih, 1024, 512, (const float*)nullptr, (const float*)nullptr,
                     proj, G4_, 1);
  hipLaunchKernelGGL(init_kernel, dim3(64), dim3(256), 0, stream,
                     ctx, hx, amax, start);

  void* args[] = {(void*)&Whh, (void*)&Wout, (void*)&bout, (void*)&proj, (void*)&basep,
                  (void*)&hx, (void*)&amax, (void*)&out};
  hipLaunchCooperativeKernel(reinterpret_cast<const void*>(decoder_main),
                             dim3(NBLK), dim3(512), args, 0, stream);
}